// Round 9
// baseline (416.505 us; speedup 1.0000x reference)
//
#include <hip/hip_runtime.h>
#include <cstdint>
#include <cmath>

// Round-17: gemm8 -- the regime-gate quadrant that pays: 256-wide tile,
// 8 waves, ring-4 fragment-linear LDS, BK=32, ONE raw s_barrier per step
// with COUNTED s_waitcnt vmcnt(2L) (never drains to 0 mid-loop). Protocol
// identical to round-16's race-audited v4, scaled to the 8-wave deep tile
// (m218/m230: counted-vmcnt pays ONLY there). gemm1=<256,256> (192 blks,
// vmcnt 8/4/0), gemm2=<128,256> (256 blks = 100% CUs, vmcnt 6/3/0).
// launch_bounds(512,2): VGPR cap 256, natural ~205 (no forced spill).
// flash_attn v6b unchanged from round 12.
//
// B=2, T=2048, D=2048, H=16, G=4, DK=128. f32 in / f32 out.
// ws (54.6 MB): xb/y [4096x2048] | WT(->WoT+VtG) [3072x2048] | qkv [4096x3072]

#define GLOBAL_AS __attribute__((address_space(1)))
#define LDS_AS __attribute__((address_space(3)))

typedef __bf16 bf16x8 __attribute__((ext_vector_type(8)));
typedef __bf16 bf16x4 __attribute__((ext_vector_type(4)));
typedef float f32x4 __attribute__((ext_vector_type(4)));
typedef float f32x16 __attribute__((ext_vector_type(16)));

constexpr int Tn = 2048;

__device__ __forceinline__ f32x4 mfma_bf16(bf16x8 a, bf16x8 b, f32x4 c) {
  return __builtin_amdgcn_mfma_f32_16x16x32_bf16(a, b, c, 0, 0, 0);
}
__device__ __forceinline__ f32x16 mfma32(bf16x8 a, bf16x8 b, f32x16 c) {
  return __builtin_amdgcn_mfma_f32_32x32x16_bf16(a, b, c, 0, 0, 0);
}
__device__ __forceinline__ uint32_t pack_bf16(float a, float b) {
  union { __bf16 h[2]; uint32_t u; } c;
  c.h[0] = (__bf16)a;
  c.h[1] = (__bf16)b;
  return c.u;
}

// ---------------------------------------------------------------- convert f32 -> bf16
__global__ __launch_bounds__(256) void convert_f32_bf16(const float* __restrict__ src,
                                                        __bf16* __restrict__ dst,
                                                        size_t n4) {
  const size_t i = (size_t)blockIdx.x * 256 + threadIdx.x;
  if (i >= n4) return;
  const f32x4 v = ((const f32x4*)src)[i];
  bf16x4 o;
#pragma unroll
  for (int k = 0; k < 4; ++k) o[k] = (__bf16)v[k];
  ((bf16x4*)dst)[i] = o;
}

// ---------------------------------------------------------------- transpose+convert
__global__ __launch_bounds__(256) void transpose_f32_bf16(const float* __restrict__ src,
                                                          __bf16* __restrict__ dst,
                                                          int K, int N) {
  __shared__ __bf16 tile[32][33];
  const int n0 = blockIdx.x * 32, k0 = blockIdx.y * 32;
  const int tx = threadIdx.x, ty = threadIdx.y;
#pragma unroll
  for (int i = 0; i < 32; i += 8)
    tile[ty + i][tx] = (__bf16)src[(size_t)(k0 + ty + i) * N + n0 + tx];
  __syncthreads();
#pragma unroll
  for (int i = 0; i < 32; i += 8)
    dst[(size_t)(n0 + ty + i) * K + k0 + tx] = tile[tx][ty + i];
}

// ---------------------------------------------------------------- transpose V (bf16)
// qkv V-slice [key][dim] -> VtG[(b*4+g)][dim][key] (stride Tn).
__global__ __launch_bounds__(256) void transpose_v(const __bf16* __restrict__ qkv,
                                                   __bf16* __restrict__ vtg) {
  __shared__ __bf16 tile[32][33];
  const int bg = blockIdx.z;
  const int b = bg >> 2, g = bg & 3;
  const int key0 = blockIdx.x * 32, d0 = blockIdx.y * 32;
  const int tx = threadIdx.x, ty = threadIdx.y;
  const __bf16* src = qkv + (size_t)b * Tn * 3072 + 2560 + g * 128;
  __bf16* dst = vtg + (size_t)bg * 128 * Tn;
#pragma unroll
  for (int i = 0; i < 32; i += 8)
    tile[ty + i][tx] = src[(size_t)(key0 + ty + i) * 3072 + d0 + tx];
  __syncthreads();
#pragma unroll
  for (int i = 0; i < 32; i += 8)
    dst[(size_t)(d0 + ty + i) * Tn + key0 + tx] = tile[tx][ty + i];
}

// ---------------------------------------------------------------- GEMM 8-wave (B^T)
// Tile BM x BN, 8 waves as 2(m) x 4(n); per-wave output (BM/2) x (BN/4).
// Ring-4 fragment-linear LDS: A group g (0..BM/16-1), chunk g*64+l holds
//   A[row g*16 + (l&15)][k (l>>4)*8 .. +8] (k rel. to step); B likewise.
// Wave w stages A groups w*GA..+GA and B groups w*GB..+GB (L = GA+GB
// global_load_lds per wave per step; LDS dest = uniform chunk base,
// HW adds lane*16 -> matches the fragment-linear read map exactly).
// Per step t: s_waitcnt vmcnt(2L) [own stage(t) done; t+1,t+2 in flight]
// -> s_barrier (collective: stage(t) fully visible) -> issue stage(t+3)
// into buf (t+3)&3 (== buf (t-1)&3, safe: all waves passed t-1's reads)
// -> MREP+NREP ds_read_b128 -> MREP*NREP MFMA. Never drains mid-loop.
template <int BM, int BN, int OUTF32>
__global__ __launch_bounds__(512, 2) void gemm8(const __bf16* __restrict__ A,
                                                const __bf16* __restrict__ BT,
                                                void* __restrict__ C,
                                                int K, int ldc) {
  constexpr int MREP = BM / 32;  // per-wave m fragments
  constexpr int NREP = BN / 64;  // per-wave n fragments
  constexpr int GA = BM / 128;   // A stage-groups per wave
  constexpr int GB = BN / 128;   // B stage-groups per wave
  constexpr int L = GA + GB;
  __shared__ __attribute__((aligned(16))) __bf16 As[4][BM * 32];
  __shared__ __attribute__((aligned(16))) __bf16 Bs[4][BN * 32];
  const int tid = threadIdx.x;
  const int wave = tid >> 6, lane = tid & 63;
  const int lr = lane & 15, lq = lane >> 4;
  const int wm = wave >> 2, wn = wave & 3;
  const int m0 = blockIdx.y * BM, n0 = blockIdx.x * BN;

  f32x4 acc[MREP][NREP] = {};

  const __bf16* ga[GA];
  const __bf16* gb[GB];
#pragma unroll
  for (int jj = 0; jj < GA; ++jj)
    ga[jj] = A + (size_t)(m0 + (wave * GA + jj) * 16 + lr) * K + lq * 8;
#pragma unroll
  for (int jj = 0; jj < GB; ++jj)
    gb[jj] = BT + (size_t)(n0 + (wave * GB + jj) * 16 + lr) * K + lq * 8;

  auto stage = [&](int buf) {
#pragma unroll
    for (int jj = 0; jj < GA; ++jj) {
      __builtin_amdgcn_global_load_lds((GLOBAL_AS void*)ga[jj],
                                       (LDS_AS void*)(&As[buf][(wave * GA + jj) * 512]),
                                       16, 0, 0);
      ga[jj] += 32;
    }
#pragma unroll
    for (int jj = 0; jj < GB; ++jj) {
      __builtin_amdgcn_global_load_lds((GLOBAL_AS void*)gb[jj],
                                       (LDS_AS void*)(&Bs[buf][(wave * GB + jj) * 512]),
                                       16, 0, 0);
      gb[jj] += 32;
    }
  };

  // ---- prologue: 3 stages in flight (3L outstanding per wave)
  stage(0);
  stage(1);
  stage(2);

  const int nstep = K >> 5;
  for (int t = 0; t < nstep; ++t) {
    if (t + 2 < nstep) {
      if constexpr (L == 4) asm volatile("s_waitcnt vmcnt(8)" ::: "memory");
      else                  asm volatile("s_waitcnt vmcnt(6)" ::: "memory");
    } else if (t + 1 < nstep) {
      if constexpr (L == 4) asm volatile("s_waitcnt vmcnt(4)" ::: "memory");
      else                  asm volatile("s_waitcnt vmcnt(3)" ::: "memory");
    } else {
      asm volatile("s_waitcnt vmcnt(0)" ::: "memory");
    }
    __builtin_amdgcn_s_barrier();
    if (t + 3 < nstep) stage((t + 3) & 3);

    const int rb = t & 3;
    bf16x8 af[MREP], bfv[NREP];
#pragma unroll
    for (int i = 0; i < MREP; ++i)
      af[i] = *(const bf16x8*)(&As[rb][((wm * MREP + i) * 64 + lane) * 8]);
#pragma unroll
    for (int j = 0; j < NREP; ++j)
      bfv[j] = *(const bf16x8*)(&Bs[rb][((wn * NREP + j) * 64 + lane) * 8]);
    __builtin_amdgcn_s_setprio(1);
#pragma unroll
    for (int i = 0; i < MREP; ++i)
#pragma unroll
      for (int j = 0; j < NREP; ++j)
        acc[i][j] = mfma_bf16(af[i], bfv[j], acc[i][j]);
    __builtin_amdgcn_s_setprio(0);
  }

#pragma unroll
  for (int i = 0; i < MREP; ++i) {
    const int row = m0 + wm * (MREP * 16) + i * 16 + lq * 4;
#pragma unroll
    for (int j = 0; j < NREP; ++j) {
      const int col = n0 + wn * (NREP * 16) + j * 16 + lr;
#pragma unroll
      for (int r = 0; r < 4; ++r) {
        if constexpr (OUTF32)
          ((float*)C)[(size_t)(row + r) * ldc + col] = acc[i][j][r];
        else
          ((__bf16*)C)[(size_t)(row + r) * ldc + col] = (__bf16)acc[i][j][r];
      }
    }
  }
}

// ---------------------------------------------------------------- RoPE
__global__ __launch_bounds__(256) void rope_kernel(__bf16* __restrict__ qkv) {
  const int row = blockIdx.x;
  const int t = row & (Tn - 1);
  for (int p = threadIdx.x; p < 1280; p += 256) {
    const int d = p & 63;
    const int hh = p >> 6;
    const int col = (hh < 16) ? (hh * 128 + d) : (2048 + (hh - 16) * 128 + d);
    const float inv = exp2f((float)d * (-13.287712379549449f / 64.f));
    const float ang = (float)t * inv;
    float sn, cs;
    __sincosf(ang, &sn, &cs);
    __bf16* ptr = qkv + (size_t)row * 3072 + col;
    const float x1 = (float)ptr[0];
    const float x2 = (float)ptr[64];
    ptr[0] = (__bf16)(x1 * cs - x2 * sn);
    ptr[64] = (__bf16)(x2 * cs + x1 * sn);
  }
}

// ---------------------------------------------------------------- flash attention v6b
// grid: (T/128, B*H), q-blocks REVERSED (longest first). 4 waves x 32 q-rows.
// KVB=64, double-buffered Ks/Vs, 2-phase schedule (one barrier per tile).
// Swapped QK^T: S^T[key][q] = mfma32(A=K-frag, B=Q-frag). 32x32 C/D layout:
// col(lane&31)=q, row=(reg&3)+8*(reg>>2)+4*(lane>>5)=key -> a lane PAIR holds
// all 64 key-scores of one q-row. Softmax: in-lane reduce + one shfl_xor(32).
// PV: O^T[d][q] = mfma32(A=V^T-frag, B=P^T-frag), P assembled in-register.
// Fragment-linear LDS: chunk c (16B) lives at Ks+c*8; HW staging writes
// (uniform base + lane*16) land chunk (base_chunk + lane) -- matches reads.
constexpr int KVB = 64;
__global__ __launch_bounds__(256, 2) void flash_attn(const __bf16* __restrict__ qkv,
                                                     const __bf16* __restrict__ vtg,
                                                     __bf16* __restrict__ y) {
  const int b = blockIdx.y >> 4, h = blockIdx.y & 15;
  const int g = h >> 2;
  const int q0 = ((int)gridDim.x - 1 - (int)blockIdx.x) * 128;  // longest blocks first
  const int tid = threadIdx.x;
  const int wave = tid >> 6, lane = tid & 63;
  const int l31 = lane & 31, hi = lane >> 5;

  const __bf16* Qb = qkv + (size_t)b * Tn * 3072 + h * 128;
  const __bf16* Kb = qkv + (size_t)b * Tn * 3072 + 2048 + g * 128;
  const __bf16* Vt = vtg + (size_t)(b * 4 + g) * 128 * Tn;  // [dim][key]

  __shared__ __attribute__((aligned(16))) __bf16 Ks[2][8192];  // 2 x 16 KB
  __shared__ __attribute__((aligned(16))) __bf16 Vs[2][8192];  // 2 x 16 KB

  // Fragment-linear chunk maps (chunk c = 16B at elem offset c*8):
  //  Ks: c=(kb*8+s)*64+lane -> K[key kb*32+(lane&31)][dim s*16+(lane>>5)*8 ..+8]
  //  Vs: c=(db*4+s)*64+lane -> V^T[dim db*32+(lane&31)][key s*16+(lane>>5)*8 ..+8]
  // Staging instr i (0..3) of wave w covers chunks [i*256+w*64, +64):
  //  K: kb=i>>1, s=(i*4+w)&7 ; V: db=i, s=w. Per-lane GLOBAL source below;
  //  LDS dest is the wave-uniform chunk base (HW adds lane*16).
  const __bf16* ksrc[4];
  const __bf16* vsrc[4];
#pragma unroll
  for (int i = 0; i < 4; ++i) {
    ksrc[i] = Kb + (size_t)((i >> 1) * 32 + l31) * 3072 + ((i * 4 + wave) & 7) * 16 + hi * 8;
    vsrc[i] = Vt + (size_t)(i * 32 + l31) * Tn + wave * 16 + hi * 8;
  }

  // Q as B-operand: lane holds Q[q = q0+wave*32+l31][k-step s: s*16 + hi*8 ..+8]
  const int qg = q0 + wave * 32 + l31;
  bf16x8 qf[8];
#pragma unroll
  for (int s = 0; s < 8; ++s)
    qf[s] = *(const bf16x8*)(Qb + (size_t)qg * 3072 + s * 16 + hi * 8);

  f32x16 o[4] = {};
  float m_i = -1e30f, l_i = 0.f;
  const float kscale = 0.12752909695983215f;  // (1/sqrt(128)) * log2(e)

  // ---- prologue: stage tile 0 into buffer 0; barrier drains vmcnt(0)
#pragma unroll
  for (int i = 0; i < 4; ++i) {
    __builtin_amdgcn_global_load_lds((GLOBAL_AS void*)ksrc[i],
                                     (LDS_AS void*)(&Ks[0][(i * 256 + wave * 64) * 8]), 16, 0, 0);
    __builtin_amdgcn_global_load_lds((GLOBAL_AS void*)vsrc[i],
                                     (LDS_AS void*)(&Vs[0][(i * 256 + wave * 64) * 8]), 16, 0, 0);
    ksrc[i] += (size_t)KVB * 3072;
    vsrc[i] += KVB;
  }
  __syncthreads();

  const int ktend = q0 + 128;
  int cur = 0;
  for (int kt = 0; kt < ktend; kt += KVB) {
    // ---- issue next-tile staging into the other buffer (overlaps compute)
    if (kt + KVB < ktend) {
#pragma unroll
      for (int i = 0; i < 4; ++i) {
        __builtin_amdgcn_global_load_lds(
            (GLOBAL_AS void*)ksrc[i],
            (LDS_AS void*)(&Ks[cur ^ 1][(i * 256 + wave * 64) * 8]), 16, 0, 0);
        __builtin_amdgcn_global_load_lds(
            (GLOBAL_AS void*)vsrc[i],
            (LDS_AS void*)(&Vs[cur ^ 1][(i * 256 + wave * 64) * 8]), 16, 0, 0);
        ksrc[i] += (size_t)KVB * 3072;
        vsrc[i] += KVB;
      }
    }

    // ---- per-wave skip of fully-masked causal tiles (wave-uniform)
    if (kt <= q0 + wave * 32 + 31) {
      // S^T = K Q^T : 2 key-blocks x 8 k-steps of 32x32x16
      f32x16 sa[2] = {};
      __builtin_amdgcn_s_setprio(1);
#pragma unroll
      for (int kb = 0; kb < 2; ++kb)
#pragma unroll
        for (int s = 0; s < 8; ++s) {
          const bf16x8 kf = *(const bf16x8*)(&Ks[cur][((kb * 8 + s) * 64 + lane) * 8]);
          sa[kb] = mfma32(kf, qf[s], sa[kb]);
        }
      __builtin_amdgcn_s_setprio(0);

      // ---- softmax (log2 domain), scores fully lane-pair-local.
      // lane's keys: kt + kb*32 + (r&3)+8*(r>>2)+4*hi.
      const bool full = (kt + KVB - 1) <= (q0 + wave * 32);  // wave-uniform
      float mx = -1e30f;
      if (full) {
#pragma unroll
        for (int kb = 0; kb < 2; ++kb)
#pragma unroll
          for (int r = 0; r < 16; ++r) {
            const float v = sa[kb][r] * kscale;
            sa[kb][r] = v;
            mx = fmaxf(mx, v);
          }
      } else {
#pragma unroll
        for (int kb = 0; kb < 2; ++kb)
#pragma unroll
          for (int r = 0; r < 16; ++r) {
            const int key = kt + kb * 32 + (r & 3) + 8 * (r >> 2) + 4 * hi;
            const float v = (key <= qg) ? sa[kb][r] * kscale : -1e30f;
            sa[kb][r] = v;
            mx = fmaxf(mx, v);
          }
      }
      mx = fmaxf(mx, __shfl_xor(mx, 32));  // combine lane pair: full 64-key max
      if (__any(mx > m_i + 8.f)) {  // defer-max: rescale only on >8 growth
        const float mnew = fmaxf(m_i, mx);
        const float alpha = __builtin_amdgcn_exp2f(m_i - mnew);
        m_i = mnew;
        l_i *= alpha;
#pragma unroll
        for (int db = 0; db < 4; ++db)
#pragma unroll
          for (int r = 0; r < 16; ++r) o[db][r] *= alpha;
      }
      float ls = 0.f;
#pragma unroll
      for (int kb = 0; kb < 2; ++kb)
#pragma unroll
        for (int r = 0; r < 16; ++r) {
          const float pv = __builtin_amdgcn_exp2f(sa[kb][r] - m_i);
          sa[kb][r] = pv;
          ls += pv;
        }
      l_i += ls;  // per-lane partial (own 32 keys); pair-combined in epilogue

      // ---- assemble P^T B-operand fragments in-register.
      // pack pairs, one symmetric xor-32 exchange, hi-select per word.
      uint32_t P[2][8], X[2][8];
#pragma unroll
      for (int kb = 0; kb < 2; ++kb)
#pragma unroll
        for (int gg = 0; gg < 8; ++gg)
          P[kb][gg] = pack_bf16(sa[kb][2 * gg], sa[kb][2 * gg + 1]);
#pragma unroll
      for (int kb = 0; kb < 2; ++kb)
#pragma unroll
        for (int gg = 0; gg < 8; ++gg)
          X[kb][gg] = (uint32_t)__shfl_xor((int)P[kb][gg], 32);

      union FU { uint32_t u[4]; bf16x8 v; };
      bf16x8 pf[4];  // k-step s: keys kt + s*16 + hi*8 ..+8
#pragma unroll
      for (int kb = 0; kb < 2; ++kb) {
        FU f0, f1;
        f0.u[0] = hi ? X[kb][2] : P[kb][0];
        f0.u[1] = hi ? X[kb][3] : P[kb][1];
        f0.u[2] = hi ? P[kb][2] : X[kb][0];
        f0.u[3] = hi ? P[kb][3] : X[kb][1];
        f1.u[0] = hi ? X[kb][6] : P[kb][4];
        f1.u[1] = hi ? X[kb][7] : P[kb][5];
        f1.u[2] = hi ? P[kb][6] : X[kb][4];
        f1.u[3] = hi ? P[kb][7] : X[kb][5];
        pf[kb * 2 + 0] = f0.v;
        pf[kb * 2 + 1] = f1.v;
      }

      // ---- O^T += V^T P^T : 4 dim-blocks x 4 k-steps of 32x32x16
      __builtin_amdgcn_s_setprio(1);
#pragma unroll
      for (int db = 0; db < 4; ++db)
#pragma unroll
        for (int s = 0; s < 4; ++s) {
          const bf16x8 vf = *(const bf16x8*)(&Vs[cur][((db * 4 + s) * 64 + lane) * 8]);
          o[db] = mfma32(vf, pf[s], o[db]);
        }
      __builtin_amdgcn_s_setprio(0);
    }

    // one barrier per tile: implicit vmcnt(0) drain = next tile staged,
    // and all waves done reading buf[cur] before it is overwritten.
    __syncthreads();
    cur ^= 1;
  }

  // ---- epilogue: pair-combine l, normalize, store (O^T: row=d, col=q)
  {
    const float lt = l_i + __shfl_xor(l_i, 32);
    const float inv = 1.0f / lt;
    __bf16* yrow = y + (size_t)(b * Tn + qg) * 2048 + h * 128;
#pragma unroll
    for (int db = 0; db < 4; ++db)
#pragma unroll
      for (int g2 = 0; g2 < 4; ++g2) {
        bf16x4 ov;
#pragma unroll
        for (int j = 0; j < 4; ++j) ov[j] = (__bf16)(o[db][4 * g2 + j] * inv);
        *(bf16x4*)(yrow + db * 32 + 8 * g2 + 4 * hi) = ov;
      }
  }
}

// ---------------------------------------------------------------- launch
extern "C" void kernel_launch(void* const* d_in, const int* in_sizes, int n_in,
                              void* d_out, int out_size, void* d_ws, size_t ws_size,
                              hipStream_t stream) {
  (void)in_sizes; (void)n_in; (void)out_size; (void)ws_size;
  const float* x  = (const float*)d_in[0];
  const float* Wq = (const float*)d_in[1];
  const float* Wk = (const float*)d_in[2];
  const float* Wv = (const float*)d_in[3];
  const float* Wo = (const float*)d_in[4];
  float* out = (float*)d_out;

  __bf16* xb  = (__bf16*)d_ws;                  // [4096][2048]; y aliases after gemm1
  __bf16* y   = xb;
  __bf16* WT  = xb + (size_t)4096 * 2048;       // [3072][2048]
  __bf16* WoT = WT;                             // [2048][2048] aliases after gemm1
  __bf16* VtG = WT + (size_t)2048 * 2048;       // [8][128][2048]
  __bf16* qkv = WT + (size_t)3072 * 2048;       // [4096][3072]

  convert_f32_bf16<<<(4096 * 2048 / 4 + 255) / 256, 256, 0, stream>>>(x, xb, 4096 * 2048 / 4);
  dim3 tb(32, 8);
  transpose_f32_bf16<<<dim3(64, 64), tb, 0, stream>>>(Wq, WT, 2048, 2048);
  transpose_f32_bf16<<<dim3(16, 64), tb, 0, stream>>>(Wk, WT + (size_t)2048 * 2048, 2048, 512);
  transpose_f32_bf16<<<dim3(16, 64), tb, 0, stream>>>(Wv, WT + (size_t)2560 * 2048, 2048, 512);

  gemm8<256, 256, 0><<<dim3(3072 / 256, 4096 / 256), 512, 0, stream>>>(xb, WT, qkv, 2048, 3072);
  rope_kernel<<<4096, 256, 0, stream>>>(qkv);

  transpose_v<<<dim3(Tn / 32, 4, 8), tb, 0, stream>>>(qkv, VtG);
  transpose_f32_bf16<<<dim3(64, 64), tb, 0, stream>>>(Wo, WoT, 2048, 2048);

  flash_attn<<<dim3(Tn / 128, 2 * 16), 256, 0, stream>>>(qkv, VtG, y);
  gemm8<128, 256, 1><<<dim3(2048 / 256, 4096 / 128), 512, 0, stream>>>(y, WoT, out, 2048, 2048);
}

// Round 10
// 383.670 us; speedup vs baseline: 1.0856x; 1.0856x over previous
//
#include <hip/hip_runtime.h>
#include <cstdint>
#include <cmath>

// Round-18: consolidation. (1) gemm reverted to the round-4 v1 structure
// (16 KB LDS, 2 barriers/K-step, high blocks/CU) -- best measured across 6
// gemm variants; schedule experiments (dbuf/counted-vmcnt/256-tile) all
// landed at ~500 TF, so bank the revert. + T1 XCD-swizzle (bijective, both
// grids %8==0): neighbor tiles share an XCD L2. (2) flash QBLK 128->256
// (8 waves): staging instrs/bytes per compute HALVED (4 gloads/wave/tile),
// softmax & P-exchange code untouched. Staging group p=i*8+wave; K:
// kb=p>>3,s=p&7; V: db=p>>2,s=p&3; dest chunk p*512 (uniform-base kept).
//
// B=2, T=2048, D=2048, H=16, G=4, DK=128. f32 in / f32 out.
// ws (54.6 MB): xb/y [4096x2048] | WT(->WoT+VtG) [3072x2048] | qkv [4096x3072]

#define GLOBAL_AS __attribute__((address_space(1)))
#define LDS_AS __attribute__((address_space(3)))

typedef __bf16 bf16x8 __attribute__((ext_vector_type(8)));
typedef __bf16 bf16x4 __attribute__((ext_vector_type(4)));
typedef float f32x4 __attribute__((ext_vector_type(4)));
typedef float f32x16 __attribute__((ext_vector_type(16)));

constexpr int Tn = 2048;

__device__ __forceinline__ f32x4 mfma_bf16(bf16x8 a, bf16x8 b, f32x4 c) {
  return __builtin_amdgcn_mfma_f32_16x16x32_bf16(a, b, c, 0, 0, 0);
}
__device__ __forceinline__ f32x16 mfma32(bf16x8 a, bf16x8 b, f32x16 c) {
  return __builtin_amdgcn_mfma_f32_32x32x16_bf16(a, b, c, 0, 0, 0);
}
__device__ __forceinline__ uint32_t pack_bf16(float a, float b) {
  union { __bf16 h[2]; uint32_t u; } c;
  c.h[0] = (__bf16)a;
  c.h[1] = (__bf16)b;
  return c.u;
}

// ---------------------------------------------------------------- convert f32 -> bf16
__global__ __launch_bounds__(256) void convert_f32_bf16(const float* __restrict__ src,
                                                        __bf16* __restrict__ dst,
                                                        size_t n4) {
  const size_t i = (size_t)blockIdx.x * 256 + threadIdx.x;
  if (i >= n4) return;
  const f32x4 v = ((const f32x4*)src)[i];
  bf16x4 o;
#pragma unroll
  for (int k = 0; k < 4; ++k) o[k] = (__bf16)v[k];
  ((bf16x4*)dst)[i] = o;
}

// ---------------------------------------------------------------- transpose+convert
__global__ __launch_bounds__(256) void transpose_f32_bf16(const float* __restrict__ src,
                                                          __bf16* __restrict__ dst,
                                                          int K, int N) {
  __shared__ __bf16 tile[32][33];
  const int n0 = blockIdx.x * 32, k0 = blockIdx.y * 32;
  const int tx = threadIdx.x, ty = threadIdx.y;
#pragma unroll
  for (int i = 0; i < 32; i += 8)
    tile[ty + i][tx] = (__bf16)src[(size_t)(k0 + ty + i) * N + n0 + tx];
  __syncthreads();
#pragma unroll
  for (int i = 0; i < 32; i += 8)
    dst[(size_t)(n0 + ty + i) * K + k0 + tx] = tile[tx][ty + i];
}

// ---------------------------------------------------------------- transpose V (bf16)
// qkv V-slice [key][dim] -> VtG[(b*4+g)][dim][key] (stride Tn).
__global__ __launch_bounds__(256) void transpose_v(const __bf16* __restrict__ qkv,
                                                   __bf16* __restrict__ vtg) {
  __shared__ __bf16 tile[32][33];
  const int bg = blockIdx.z;
  const int b = bg >> 2, g = bg & 3;
  const int key0 = blockIdx.x * 32, d0 = blockIdx.y * 32;
  const int tx = threadIdx.x, ty = threadIdx.y;
  const __bf16* src = qkv + (size_t)b * Tn * 3072 + 2560 + g * 128;
  __bf16* dst = vtg + (size_t)bg * 128 * Tn;
#pragma unroll
  for (int i = 0; i < 32; i += 8)
    tile[ty + i][tx] = src[(size_t)(key0 + ty + i) * 3072 + d0 + tx];
  __syncthreads();
#pragma unroll
  for (int i = 0; i < 32; i += 8)
    dst[(size_t)(d0 + ty + i) * Tn + key0 + tx] = tile[tx][ty + i];
}

// ---------------------------------------------------------------- GEMM (B^T) v1+swz
// Round-4's best-measured structure, unchanged, plus bijective XCD swizzle
// (nwg%8==0 for both call sites: 768 and 512).
__global__ __launch_bounds__(256) void gemm_bt(const __bf16* __restrict__ A,
                                               const __bf16* __restrict__ BT,
                                               void* __restrict__ C,
                                               int K, int ldc, int outf32) {
  __shared__ __attribute__((aligned(16))) __bf16 As[128 * 32];
  __shared__ __attribute__((aligned(16))) __bf16 Bs[128 * 32];
  const int tid = threadIdx.x;
  const int wave = tid >> 6, lane = tid & 63;
  const int lr = lane & 15, lq = lane >> 4;
  const int wm = wave >> 1, wn = wave & 1;

  // T1: XCD-aware chunked remap. HW block n -> XCD n&7; logical id
  // lid = (n&7)*cpx + (n>>3) gives each XCD a contiguous logical chunk.
  const int gx = gridDim.x;
  const int nwg = gx * (int)gridDim.y;
  const int bid = (int)blockIdx.y * gx + (int)blockIdx.x;
  const int cpx = nwg >> 3;
  const int lid = (bid & 7) * cpx + (bid >> 3);
  const int m0 = (lid / gx) * 128, n0 = (lid % gx) * 128;

  f32x4 acc[4][4] = {};

  const int srow = tid >> 2;
  const int scol = (tid & 3) * 8;
  const __bf16* ga = A + (size_t)(m0 + srow) * K + scol;
  const __bf16* gb = BT + (size_t)(n0 + srow) * K + scol;

  for (int kt = 0; kt < K; kt += 32) {
    __syncthreads();
#pragma unroll
    for (int it = 0; it < 2; ++it) {
      __builtin_amdgcn_global_load_lds((GLOBAL_AS void*)(ga + (size_t)it * 64 * K + kt),
                                       (LDS_AS void*)(As + it * 2048 + wave * 512), 16, 0, 0);
      __builtin_amdgcn_global_load_lds((GLOBAL_AS void*)(gb + (size_t)it * 64 * K + kt),
                                       (LDS_AS void*)(Bs + it * 2048 + wave * 512), 16, 0, 0);
    }
    __syncthreads();

    bf16x8 af[4], bfv[4];
#pragma unroll
    for (int i = 0; i < 4; ++i)
      af[i] = *(const bf16x8*)(As + (wm * 64 + i * 16 + lr) * 32 + lq * 8);
#pragma unroll
    for (int j = 0; j < 4; ++j)
      bfv[j] = *(const bf16x8*)(Bs + (wn * 64 + j * 16 + lr) * 32 + lq * 8);
#pragma unroll
    for (int i = 0; i < 4; ++i)
#pragma unroll
      for (int j = 0; j < 4; ++j)
        acc[i][j] = mfma_bf16(af[i], bfv[j], acc[i][j]);
  }

#pragma unroll
  for (int i = 0; i < 4; ++i) {
    const int row = m0 + wm * 64 + i * 16 + lq * 4;
#pragma unroll
    for (int j = 0; j < 4; ++j) {
      const int col = n0 + wn * 64 + j * 16 + lr;
#pragma unroll
      for (int r = 0; r < 4; ++r) {
        if (outf32)
          ((float*)C)[(size_t)(row + r) * ldc + col] = acc[i][j][r];
        else
          ((__bf16*)C)[(size_t)(row + r) * ldc + col] = (__bf16)acc[i][j][r];
      }
    }
  }
}

// ---------------------------------------------------------------- RoPE
__global__ __launch_bounds__(256) void rope_kernel(__bf16* __restrict__ qkv) {
  const int row = blockIdx.x;
  const int t = row & (Tn - 1);
  for (int p = threadIdx.x; p < 1280; p += 256) {
    const int d = p & 63;
    const int hh = p >> 6;
    const int col = (hh < 16) ? (hh * 128 + d) : (2048 + (hh - 16) * 128 + d);
    const float inv = exp2f((float)d * (-13.287712379549449f / 64.f));
    const float ang = (float)t * inv;
    float sn, cs;
    __sincosf(ang, &sn, &cs);
    __bf16* ptr = qkv + (size_t)row * 3072 + col;
    const float x1 = (float)ptr[0];
    const float x2 = (float)ptr[64];
    ptr[0] = (__bf16)(x1 * cs - x2 * sn);
    ptr[64] = (__bf16)(x2 * cs + x1 * sn);
  }
}

// ---------------------------------------------------------------- flash attention v7
// grid: (T/256, B*H), q-blocks REVERSED (longest first). 8 waves x 32 q-rows
// (QBLK=256). KVB=64, double-buffered Ks/Vs, 2-phase schedule (one barrier
// per tile). Same per-wave math as v6b (swapped QK^T, in-register softmax,
// in-register P exchange); staging halved per unit compute: 4 gloads/wave.
// Staging group p = i*8 + wave (i=0..1):
//   K: kb=p>>3, s=p&7 -> src K[kb*32+l31][s*16+hi*8], dest chunk p*64
//   V: db=p>>2, s=p&3 -> src V^T[db*32+l31][s*16+hi*8], dest chunk p*64
constexpr int KVB = 64;
__global__ __launch_bounds__(512, 2) void flash_attn(const __bf16* __restrict__ qkv,
                                                     const __bf16* __restrict__ vtg,
                                                     __bf16* __restrict__ y) {
  const int b = blockIdx.y >> 4, h = blockIdx.y & 15;
  const int g = h >> 2;
  const int q0 = ((int)gridDim.x - 1 - (int)blockIdx.x) * 256;  // longest blocks first
  const int tid = threadIdx.x;
  const int wave = tid >> 6, lane = tid & 63;
  const int l31 = lane & 31, hi = lane >> 5;

  const __bf16* Qb = qkv + (size_t)b * Tn * 3072 + h * 128;
  const __bf16* Kb = qkv + (size_t)b * Tn * 3072 + 2048 + g * 128;
  const __bf16* Vt = vtg + (size_t)(b * 4 + g) * 128 * Tn;  // [dim][key]

  __shared__ __attribute__((aligned(16))) __bf16 Ks[2][8192];  // 2 x 16 KB
  __shared__ __attribute__((aligned(16))) __bf16 Vs[2][8192];  // 2 x 16 KB

  // staging sources: instr i (0..1) of wave w covers chunk group p = i*8+w.
  const __bf16* ksrc[2];
  const __bf16* vsrc[2];
#pragma unroll
  for (int i = 0; i < 2; ++i) {
    const int p = i * 8 + wave;
    ksrc[i] = Kb + (size_t)((p >> 3) * 32 + l31) * 3072 + (p & 7) * 16 + hi * 8;
    vsrc[i] = Vt + (size_t)((p >> 2) * 32 + l31) * Tn + (p & 3) * 16 + hi * 8;
  }

  // Q as B-operand: lane holds Q[q = q0+wave*32+l31][k-step s: s*16 + hi*8 ..+8]
  const int qg = q0 + wave * 32 + l31;
  bf16x8 qf[8];
#pragma unroll
  for (int s = 0; s < 8; ++s)
    qf[s] = *(const bf16x8*)(Qb + (size_t)qg * 3072 + s * 16 + hi * 8);

  f32x16 o[4] = {};
  float m_i = -1e30f, l_i = 0.f;
  const float kscale = 0.12752909695983215f;  // (1/sqrt(128)) * log2(e)

  // ---- prologue: stage tile 0 into buffer 0; barrier drains vmcnt(0)
#pragma unroll
  for (int i = 0; i < 2; ++i) {
    const int p = i * 8 + wave;
    __builtin_amdgcn_global_load_lds((GLOBAL_AS void*)ksrc[i],
                                     (LDS_AS void*)(&Ks[0][p * 512]), 16, 0, 0);
    __builtin_amdgcn_global_load_lds((GLOBAL_AS void*)vsrc[i],
                                     (LDS_AS void*)(&Vs[0][p * 512]), 16, 0, 0);
    ksrc[i] += (size_t)KVB * 3072;
    vsrc[i] += KVB;
  }
  __syncthreads();

  const int ktend = q0 + 256;
  int cur = 0;
  for (int kt = 0; kt < ktend; kt += KVB) {
    // ---- issue next-tile staging into the other buffer (overlaps compute)
    if (kt + KVB < ktend) {
#pragma unroll
      for (int i = 0; i < 2; ++i) {
        const int p = i * 8 + wave;
        __builtin_amdgcn_global_load_lds((GLOBAL_AS void*)ksrc[i],
                                         (LDS_AS void*)(&Ks[cur ^ 1][p * 512]), 16, 0, 0);
        __builtin_amdgcn_global_load_lds((GLOBAL_AS void*)vsrc[i],
                                         (LDS_AS void*)(&Vs[cur ^ 1][p * 512]), 16, 0, 0);
        ksrc[i] += (size_t)KVB * 3072;
        vsrc[i] += KVB;
      }
    }

    // ---- per-wave skip of fully-masked causal tiles (wave-uniform)
    if (kt <= q0 + wave * 32 + 31) {
      // S^T = K Q^T : 2 key-blocks x 8 k-steps of 32x32x16
      f32x16 sa[2] = {};
      __builtin_amdgcn_s_setprio(1);
#pragma unroll
      for (int kb = 0; kb < 2; ++kb)
#pragma unroll
        for (int s = 0; s < 8; ++s) {
          const bf16x8 kf = *(const bf16x8*)(&Ks[cur][((kb * 8 + s) * 64 + lane) * 8]);
          sa[kb] = mfma32(kf, qf[s], sa[kb]);
        }
      __builtin_amdgcn_s_setprio(0);

      // ---- softmax (log2 domain), scores fully lane-pair-local.
      // lane's keys: kt + kb*32 + (r&3)+8*(r>>2)+4*hi.
      const bool full = (kt + KVB - 1) <= (q0 + wave * 32);  // wave-uniform
      float mx = -1e30f;
      if (full) {
#pragma unroll
        for (int kb = 0; kb < 2; ++kb)
#pragma unroll
          for (int r = 0; r < 16; ++r) {
            const float v = sa[kb][r] * kscale;
            sa[kb][r] = v;
            mx = fmaxf(mx, v);
          }
      } else {
#pragma unroll
        for (int kb = 0; kb < 2; ++kb)
#pragma unroll
          for (int r = 0; r < 16; ++r) {
            const int key = kt + kb * 32 + (r & 3) + 8 * (r >> 2) + 4 * hi;
            const float v = (key <= qg) ? sa[kb][r] * kscale : -1e30f;
            sa[kb][r] = v;
            mx = fmaxf(mx, v);
          }
      }
      mx = fmaxf(mx, __shfl_xor(mx, 32));  // combine lane pair: full 64-key max
      if (__any(mx > m_i + 8.f)) {  // defer-max: rescale only on >8 growth
        const float mnew = fmaxf(m_i, mx);
        const float alpha = __builtin_amdgcn_exp2f(m_i - mnew);
        m_i = mnew;
        l_i *= alpha;
#pragma unroll
        for (int db = 0; db < 4; ++db)
#pragma unroll
          for (int r = 0; r < 16; ++r) o[db][r] *= alpha;
      }
      float ls = 0.f;
#pragma unroll
      for (int kb = 0; kb < 2; ++kb)
#pragma unroll
        for (int r = 0; r < 16; ++r) {
          const float pv = __builtin_amdgcn_exp2f(sa[kb][r] - m_i);
          sa[kb][r] = pv;
          ls += pv;
        }
      l_i += ls;  // per-lane partial (own 32 keys); pair-combined in epilogue

      // ---- assemble P^T B-operand fragments in-register.
      // pack pairs, one symmetric xor-32 exchange, hi-select per word.
      uint32_t P[2][8], X[2][8];
#pragma unroll
      for (int kb = 0; kb < 2; ++kb)
#pragma unroll
        for (int gg = 0; gg < 8; ++gg)
          P[kb][gg] = pack_bf16(sa[kb][2 * gg], sa[kb][2 * gg + 1]);
#pragma unroll
      for (int kb = 0; kb < 2; ++kb)
#pragma unroll
        for (int gg = 0; gg < 8; ++gg)
          X[kb][gg] = (uint32_t)__shfl_xor((int)P[kb][gg], 32);

      union FU { uint32_t u[4]; bf16x8 v; };
      bf16x8 pf[4];  // k-step s: keys kt + s*16 + hi*8 ..+8
#pragma unroll
      for (int kb = 0; kb < 2; ++kb) {
        FU f0, f1;
        f0.u[0] = hi ? X[kb][2] : P[kb][0];
        f0.u[1] = hi ? X[kb][3] : P[kb][1];
        f0.u[2] = hi ? P[kb][2] : X[kb][0];
        f0.u[3] = hi ? P[kb][3] : X[kb][1];
        f1.u[0] = hi ? X[kb][6] : P[kb][4];
        f1.u[1] = hi ? X[kb][7] : P[kb][5];
        f1.u[2] = hi ? P[kb][6] : X[kb][4];
        f1.u[3] = hi ? P[kb][7] : X[kb][5];
        pf[kb * 2 + 0] = f0.v;
        pf[kb * 2 + 1] = f1.v;
      }

      // ---- O^T += V^T P^T : 4 dim-blocks x 4 k-steps of 32x32x16
      __builtin_amdgcn_s_setprio(1);
#pragma unroll
      for (int db = 0; db < 4; ++db)
#pragma unroll
        for (int s = 0; s < 4; ++s) {
          const bf16x8 vf = *(const bf16x8*)(&Vs[cur][((db * 4 + s) * 64 + lane) * 8]);
          o[db] = mfma32(vf, pf[s], o[db]);
        }
      __builtin_amdgcn_s_setprio(0);
    }

    // one barrier per tile: implicit vmcnt(0) drain = next tile staged,
    // and all waves done reading buf[cur] before it is overwritten.
    __syncthreads();
    cur ^= 1;
  }

  // ---- epilogue: pair-combine l, normalize, store (O^T: row=d, col=q)
  {
    const float lt = l_i + __shfl_xor(l_i, 32);
    const float inv = 1.0f / lt;
    __bf16* yrow = y + (size_t)(b * Tn + qg) * 2048 + h * 128;
#pragma unroll
    for (int db = 0; db < 4; ++db)
#pragma unroll
      for (int g2 = 0; g2 < 4; ++g2) {
        bf16x4 ov;
#pragma unroll
        for (int j = 0; j < 4; ++j) ov[j] = (__bf16)(o[db][4 * g2 + j] * inv);
        *(bf16x4*)(yrow + db * 32 + 8 * g2 + 4 * hi) = ov;
      }
  }
}

// ---------------------------------------------------------------- launch
extern "C" void kernel_launch(void* const* d_in, const int* in_sizes, int n_in,
                              void* d_out, int out_size, void* d_ws, size_t ws_size,
                              hipStream_t stream) {
  (void)in_sizes; (void)n_in; (void)out_size; (void)ws_size;
  const float* x  = (const float*)d_in[0];
  const float* Wq = (const float*)d_in[1];
  const float* Wk = (const float*)d_in[2];
  const float* Wv = (const float*)d_in[3];
  const float* Wo = (const float*)d_in[4];
  float* out = (float*)d_out;

  __bf16* xb  = (__bf16*)d_ws;                  // [4096][2048]; y aliases after gemm1
  __bf16* y   = xb;
  __bf16* WT  = xb + (size_t)4096 * 2048;       // [3072][2048]
  __bf16* WoT = WT;                             // [2048][2048] aliases after gemm1
  __bf16* VtG = WT + (size_t)2048 * 2048;       // [8][128][2048]
  __bf16* qkv = WT + (size_t)3072 * 2048;       // [4096][3072]

  convert_f32_bf16<<<(4096 * 2048 / 4 + 255) / 256, 256, 0, stream>>>(x, xb, 4096 * 2048 / 4);
  dim3 tb(32, 8);
  transpose_f32_bf16<<<dim3(64, 64), tb, 0, stream>>>(Wq, WT, 2048, 2048);
  transpose_f32_bf16<<<dim3(16, 64), tb, 0, stream>>>(Wk, WT + (size_t)2048 * 2048, 2048, 512);
  transpose_f32_bf16<<<dim3(16, 64), tb, 0, stream>>>(Wv, WT + (size_t)2560 * 2048, 2048, 512);

  gemm_bt<<<dim3(3072 / 128, 4096 / 128), 256, 0, stream>>>(xb, WT, qkv, 2048, 3072, 0);
  rope_kernel<<<4096, 256, 0, stream>>>(qkv);

  transpose_v<<<dim3(Tn / 32, 4, 8), tb, 0, stream>>>(qkv, VtG);
  transpose_f32_bf16<<<dim3(64, 64), tb, 0, stream>>>(Wo, WoT, 2048, 2048);

  flash_attn<<<dim3(Tn / 256, 2 * 16), 512, 0, stream>>>(qkv, VtG, y);
  gemm_bt<<<dim3(2048 / 128, 4096 / 128), 256, 0, stream>>>(y, WoT, out, 2048, 2048, 1);
}

// Round 12
// 380.833 us; speedup vs baseline: 1.0937x; 1.0074x over previous
//
#include <hip/hip_runtime.h>
#include <cstdint>
#include <cmath>

// Round-20: round-19 with the workspace-aliasing bug fixed. Root cause of
// r19's absmax=1.6: tab aliases the WkT/WvT slice of WT; launching
// rope_table BEFORE the Wk transpose let transpose_f32_bf16(Wk) overwrite
// the table, so rope rotated with garbage. Fix: launch rope_table AFTER
// gemm1 (WkT consumed, region dead) and BEFORE rope_kernel. transpose_v
// then overwrites the region (tab no longer needed). All kernels identical
// to round 19: gemm v1 (round-4 best), flash v6c (v6b minus scale pass),
// table-driven rope with kscale folded into Q.
//
// B=2, T=2048, D=2048, H=16, G=4, DK=128. f32 in / f32 out.
// ws (54.6 MB): xb/y [4096x2048] | WT(->WoT+VtG) [3072x2048] | qkv [4096x3072]

#define GLOBAL_AS __attribute__((address_space(1)))
#define LDS_AS __attribute__((address_space(3)))

typedef __bf16 bf16x8 __attribute__((ext_vector_type(8)));
typedef __bf16 bf16x4 __attribute__((ext_vector_type(4)));
typedef float f32x4 __attribute__((ext_vector_type(4)));
typedef float f32x16 __attribute__((ext_vector_type(16)));

constexpr int Tn = 2048;

__device__ __forceinline__ f32x4 mfma_bf16(bf16x8 a, bf16x8 b, f32x4 c) {
  return __builtin_amdgcn_mfma_f32_16x16x32_bf16(a, b, c, 0, 0, 0);
}
__device__ __forceinline__ f32x16 mfma32(bf16x8 a, bf16x8 b, f32x16 c) {
  return __builtin_amdgcn_mfma_f32_32x32x16_bf16(a, b, c, 0, 0, 0);
}
__device__ __forceinline__ uint32_t pack_bf16(float a, float b) {
  union { __bf16 h[2]; uint32_t u; } c;
  c.h[0] = (__bf16)a;
  c.h[1] = (__bf16)b;
  return c.u;
}

// ---------------------------------------------------------------- convert f32 -> bf16
__global__ __launch_bounds__(256) void convert_f32_bf16(const float* __restrict__ src,
                                                        __bf16* __restrict__ dst,
                                                        size_t n4) {
  const size_t i = (size_t)blockIdx.x * 256 + threadIdx.x;
  if (i >= n4) return;
  const f32x4 v = ((const f32x4*)src)[i];
  bf16x4 o;
#pragma unroll
  for (int k = 0; k < 4; ++k) o[k] = (__bf16)v[k];
  ((bf16x4*)dst)[i] = o;
}

// ---------------------------------------------------------------- transpose+convert
__global__ __launch_bounds__(256) void transpose_f32_bf16(const float* __restrict__ src,
                                                          __bf16* __restrict__ dst,
                                                          int K, int N) {
  __shared__ __bf16 tile[32][33];
  const int n0 = blockIdx.x * 32, k0 = blockIdx.y * 32;
  const int tx = threadIdx.x, ty = threadIdx.y;
#pragma unroll
  for (int i = 0; i < 32; i += 8)
    tile[ty + i][tx] = (__bf16)src[(size_t)(k0 + ty + i) * N + n0 + tx];
  __syncthreads();
#pragma unroll
  for (int i = 0; i < 32; i += 8)
    dst[(size_t)(n0 + ty + i) * K + k0 + tx] = tile[tx][ty + i];
}

// ---------------------------------------------------------------- transpose V (bf16)
// qkv V-slice [key][dim] -> VtG[(b*4+g)][dim][key] (stride Tn).
__global__ __launch_bounds__(256) void transpose_v(const __bf16* __restrict__ qkv,
                                                   __bf16* __restrict__ vtg) {
  __shared__ __bf16 tile[32][33];
  const int bg = blockIdx.z;
  const int b = bg >> 2, g = bg & 3;
  const int key0 = blockIdx.x * 32, d0 = blockIdx.y * 32;
  const int tx = threadIdx.x, ty = threadIdx.y;
  const __bf16* src = qkv + (size_t)b * Tn * 3072 + 2560 + g * 128;
  __bf16* dst = vtg + (size_t)bg * 128 * Tn;
#pragma unroll
  for (int i = 0; i < 32; i += 8)
    tile[ty + i][tx] = src[(size_t)(key0 + ty + i) * 3072 + d0 + tx];
  __syncthreads();
#pragma unroll
  for (int i = 0; i < 32; i += 8)
    dst[(size_t)(d0 + ty + i) * Tn + key0 + tx] = tile[tx][ty + i];
}

// ---------------------------------------------------------------- GEMM (B^T)
// Round-4's best-measured structure, byte-identical.
__global__ __launch_bounds__(256) void gemm_bt(const __bf16* __restrict__ A,
                                               const __bf16* __restrict__ BT,
                                               void* __restrict__ C,
                                               int K, int ldc, int outf32) {
  __shared__ __attribute__((aligned(16))) __bf16 As[128 * 32];
  __shared__ __attribute__((aligned(16))) __bf16 Bs[128 * 32];
  const int tid = threadIdx.x;
  const int wave = tid >> 6, lane = tid & 63;
  const int lr = lane & 15, lq = lane >> 4;
  const int wm = wave >> 1, wn = wave & 1;
  const int m0 = blockIdx.y * 128, n0 = blockIdx.x * 128;

  f32x4 acc[4][4] = {};

  const int srow = tid >> 2;
  const int scol = (tid & 3) * 8;
  const __bf16* ga = A + (size_t)(m0 + srow) * K + scol;
  const __bf16* gb = BT + (size_t)(n0 + srow) * K + scol;

  for (int kt = 0; kt < K; kt += 32) {
    __syncthreads();
#pragma unroll
    for (int it = 0; it < 2; ++it) {
      __builtin_amdgcn_global_load_lds((GLOBAL_AS void*)(ga + (size_t)it * 64 * K + kt),
                                       (LDS_AS void*)(As + it * 2048 + wave * 512), 16, 0, 0);
      __builtin_amdgcn_global_load_lds((GLOBAL_AS void*)(gb + (size_t)it * 64 * K + kt),
                                       (LDS_AS void*)(Bs + it * 2048 + wave * 512), 16, 0, 0);
    }
    __syncthreads();

    bf16x8 af[4], bfv[4];
#pragma unroll
    for (int i = 0; i < 4; ++i)
      af[i] = *(const bf16x8*)(As + (wm * 64 + i * 16 + lr) * 32 + lq * 8);
#pragma unroll
    for (int j = 0; j < 4; ++j)
      bfv[j] = *(const bf16x8*)(Bs + (wn * 64 + j * 16 + lr) * 32 + lq * 8);
#pragma unroll
    for (int i = 0; i < 4; ++i)
#pragma unroll
      for (int j = 0; j < 4; ++j)
        acc[i][j] = mfma_bf16(af[i], bfv[j], acc[i][j]);
  }

#pragma unroll
  for (int i = 0; i < 4; ++i) {
    const int row = m0 + wm * 64 + i * 16 + lq * 4;
#pragma unroll
    for (int j = 0; j < 4; ++j) {
      const int col = n0 + wn * 64 + j * 16 + lr;
#pragma unroll
      for (int r = 0; r < 4; ++r) {
        if (outf32)
          ((float*)C)[(size_t)(row + r) * ldc + col] = acc[i][j][r];
        else
          ((__bf16*)C)[(size_t)(row + r) * ldc + col] = (__bf16)acc[i][j][r];
      }
    }
  }
}

// ---------------------------------------------------------------- RoPE table
// tab[t][d] = {cos, sin} of t * theta^(-2d/128); 2048 x 64 float2 (1 MB).
// MUST launch after gemm1 (tab aliases the then-dead WkT region) and
// before rope_kernel.
__global__ __launch_bounds__(64) void rope_table(float* __restrict__ tab) {
  const int t = blockIdx.x;
  const int d = threadIdx.x;
  const float inv = exp2f((float)d * (-13.287712379549449f / 64.f));
  const float ang = (float)t * inv;
  float sn, cs;
  __sincosf(ang, &sn, &cs);
  ((float2*)tab)[t * 64 + d] = make_float2(cs, sn);
}

// ---------------------------------------------------------------- RoPE (table-driven)
// Q rows additionally scaled by kscale = (1/sqrt(128))*log2(e) -- flash's
// softmax then works directly on S (scale pre-folded into Q).
__global__ __launch_bounds__(256) void rope_kernel(__bf16* __restrict__ qkv,
                                                   const float* __restrict__ tab) {
  const int row = blockIdx.x;
  const int t = row & (Tn - 1);
  const float kscale = 0.12752909695983215f;
  for (int p = threadIdx.x; p < 1280; p += 256) {
    const int d = p & 63;
    const int hh = p >> 6;
    const bool isq = hh < 16;
    const int col = isq ? (hh * 128 + d) : (2048 + (hh - 16) * 128 + d);
    const float2 cst = ((const float2*)tab)[t * 64 + d];
    const float s = isq ? kscale : 1.0f;
    __bf16* ptr = qkv + (size_t)row * 3072 + col;
    const float x1 = (float)ptr[0];
    const float x2 = (float)ptr[64];
    ptr[0] = (__bf16)((x1 * cst.x - x2 * cst.y) * s);
    ptr[64] = (__bf16)((x2 * cst.x + x1 * cst.y) * s);
  }
}

// ---------------------------------------------------------------- flash attention v6c
// v6b (round-12, best measured 102.6 us) with the per-tile kscale pass
// deleted (scale folded into Q by rope). Everything else identical:
// grid (T/128, B*H) reversed, 4 waves x 32 q-rows, KVB=64, double-buffered
// fragment-linear Ks/Vs, swapped QK^T (S^T = mfma32(K,Q)), in-register
// softmax (one shfl_xor(32)/tile), in-register P pack+exchange, PV via
// O^T = mfma32(V^T, P^T).
constexpr int KVB = 64;
__global__ __launch_bounds__(256, 2) void flash_attn(const __bf16* __restrict__ qkv,
                                                     const __bf16* __restrict__ vtg,
                                                     __bf16* __restrict__ y) {
  const int b = blockIdx.y >> 4, h = blockIdx.y & 15;
  const int g = h >> 2;
  const int q0 = ((int)gridDim.x - 1 - (int)blockIdx.x) * 128;  // longest blocks first
  const int tid = threadIdx.x;
  const int wave = tid >> 6, lane = tid & 63;
  const int l31 = lane & 31, hi = lane >> 5;

  const __bf16* Qb = qkv + (size_t)b * Tn * 3072 + h * 128;
  const __bf16* Kb = qkv + (size_t)b * Tn * 3072 + 2048 + g * 128;
  const __bf16* Vt = vtg + (size_t)(b * 4 + g) * 128 * Tn;  // [dim][key]

  __shared__ __attribute__((aligned(16))) __bf16 Ks[2][8192];  // 2 x 16 KB
  __shared__ __attribute__((aligned(16))) __bf16 Vs[2][8192];  // 2 x 16 KB

  // Fragment-linear chunk maps (chunk c = 16B at elem offset c*8):
  //  Ks: c=(kb*8+s)*64+lane -> K[key kb*32+(lane&31)][dim s*16+(lane>>5)*8 ..+8]
  //  Vs: c=(db*4+s)*64+lane -> V^T[dim db*32+(lane&31)][key s*16+(lane>>5)*8 ..+8]
  // Staging instr i (0..3) of wave w covers chunks [i*256+w*64, +64):
  //  K: kb=i>>1, s=(i*4+w)&7 ; V: db=i, s=w. Per-lane GLOBAL source below;
  //  LDS dest is the wave-uniform chunk base (HW adds lane*16).
  const __bf16* ksrc[4];
  const __bf16* vsrc[4];
#pragma unroll
  for (int i = 0; i < 4; ++i) {
    ksrc[i] = Kb + (size_t)((i >> 1) * 32 + l31) * 3072 + ((i * 4 + wave) & 7) * 16 + hi * 8;
    vsrc[i] = Vt + (size_t)(i * 32 + l31) * Tn + wave * 16 + hi * 8;
  }

  // Q as B-operand: lane holds Q[q = q0+wave*32+l31][k-step s: s*16 + hi*8 ..+8]
  const int qg = q0 + wave * 32 + l31;
  bf16x8 qf[8];
#pragma unroll
  for (int s = 0; s < 8; ++s)
    qf[s] = *(const bf16x8*)(Qb + (size_t)qg * 3072 + s * 16 + hi * 8);

  f32x16 o[4] = {};
  float m_i = -1e30f, l_i = 0.f;

  // ---- prologue: stage tile 0 into buffer 0; barrier drains vmcnt(0)
#pragma unroll
  for (int i = 0; i < 4; ++i) {
    __builtin_amdgcn_global_load_lds((GLOBAL_AS void*)ksrc[i],
                                     (LDS_AS void*)(&Ks[0][(i * 256 + wave * 64) * 8]), 16, 0, 0);
    __builtin_amdgcn_global_load_lds((GLOBAL_AS void*)vsrc[i],
                                     (LDS_AS void*)(&Vs[0][(i * 256 + wave * 64) * 8]), 16, 0, 0);
    ksrc[i] += (size_t)KVB * 3072;
    vsrc[i] += KVB;
  }
  __syncthreads();

  const int ktend = q0 + 128;
  int cur = 0;
  for (int kt = 0; kt < ktend; kt += KVB) {
    // ---- issue next-tile staging into the other buffer (overlaps compute)
    if (kt + KVB < ktend) {
#pragma unroll
      for (int i = 0; i < 4; ++i) {
        __builtin_amdgcn_global_load_lds(
            (GLOBAL_AS void*)ksrc[i],
            (LDS_AS void*)(&Ks[cur ^ 1][(i * 256 + wave * 64) * 8]), 16, 0, 0);
        __builtin_amdgcn_global_load_lds(
            (GLOBAL_AS void*)vsrc[i],
            (LDS_AS void*)(&Vs[cur ^ 1][(i * 256 + wave * 64) * 8]), 16, 0, 0);
        ksrc[i] += (size_t)KVB * 3072;
        vsrc[i] += KVB;
      }
    }

    // ---- per-wave skip of fully-masked causal tiles (wave-uniform)
    if (kt <= q0 + wave * 32 + 31) {
      // S^T = K Q^T : 2 key-blocks x 8 k-steps of 32x32x16 (scale in Q)
      f32x16 sa[2] = {};
      __builtin_amdgcn_s_setprio(1);
#pragma unroll
      for (int kb = 0; kb < 2; ++kb)
#pragma unroll
        for (int s = 0; s < 8; ++s) {
          const bf16x8 kf = *(const bf16x8*)(&Ks[cur][((kb * 8 + s) * 64 + lane) * 8]);
          sa[kb] = mfma32(kf, qf[s], sa[kb]);
        }
      __builtin_amdgcn_s_setprio(0);

      // ---- softmax (log2 domain), scores fully lane-pair-local.
      // lane's keys: kt + kb*32 + (r&3)+8*(r>>2)+4*hi.
      const bool full = (kt + KVB - 1) <= (q0 + wave * 32);  // wave-uniform
      float mx = -1e30f;
      if (full) {
#pragma unroll
        for (int kb = 0; kb < 2; ++kb)
#pragma unroll
          for (int r = 0; r < 16; ++r) mx = fmaxf(mx, sa[kb][r]);
      } else {
#pragma unroll
        for (int kb = 0; kb < 2; ++kb)
#pragma unroll
          for (int r = 0; r < 16; ++r) {
            const int key = kt + kb * 32 + (r & 3) + 8 * (r >> 2) + 4 * hi;
            const float v = (key <= qg) ? sa[kb][r] : -1e30f;
            sa[kb][r] = v;
            mx = fmaxf(mx, v);
          }
      }
      mx = fmaxf(mx, __shfl_xor(mx, 32));  // combine lane pair: full 64-key max
      if (__any(mx > m_i + 8.f)) {  // defer-max: rescale only on >8 growth
        const float mnew = fmaxf(m_i, mx);
        const float alpha = __builtin_amdgcn_exp2f(m_i - mnew);
        m_i = mnew;
        l_i *= alpha;
#pragma unroll
        for (int db = 0; db < 4; ++db)
#pragma unroll
          for (int r = 0; r < 16; ++r) o[db][r] *= alpha;
      }
      float ls = 0.f;
#pragma unroll
      for (int kb = 0; kb < 2; ++kb)
#pragma unroll
        for (int r = 0; r < 16; ++r) {
          const float pv = __builtin_amdgcn_exp2f(sa[kb][r] - m_i);
          sa[kb][r] = pv;
          ls += pv;
        }
      l_i += ls;  // per-lane partial (own 32 keys); pair-combined in epilogue

      // ---- assemble P^T B-operand fragments in-register.
      // pack pairs, one symmetric xor-32 exchange, hi-select per word.
      uint32_t P[2][8], X[2][8];
#pragma unroll
      for (int kb = 0; kb < 2; ++kb)
#pragma unroll
        for (int gg = 0; gg < 8; ++gg)
          P[kb][gg] = pack_bf16(sa[kb][2 * gg], sa[kb][2 * gg + 1]);
#pragma unroll
      for (int kb = 0; kb < 2; ++kb)
#pragma unroll
        for (int gg = 0; gg < 8; ++gg)
          X[kb][gg] = (uint32_t)__shfl_xor((int)P[kb][gg], 32);

      union FU { uint32_t u[4]; bf16x8 v; };
      bf16x8 pf[4];  // k-step s: keys kt + s*16 + hi*8 ..+8
#pragma unroll
      for (int kb = 0; kb < 2; ++kb) {
        FU f0, f1;
        f0.u[0] = hi ? X[kb][2] : P[kb][0];
        f0.u[1] = hi ? X[kb][3] : P[kb][1];
        f0.u[2] = hi ? P[kb][2] : X[kb][0];
        f0.u[3] = hi ? P[kb][3] : X[kb][1];
        f1.u[0] = hi ? X[kb][6] : P[kb][4];
        f1.u[1] = hi ? X[kb][7] : P[kb][5];
        f1.u[2] = hi ? P[kb][6] : X[kb][4];
        f1.u[3] = hi ? P[kb][7] : X[kb][5];
        pf[kb * 2 + 0] = f0.v;
        pf[kb * 2 + 1] = f1.v;
      }

      // ---- O^T += V^T P^T : 4 dim-blocks x 4 k-steps of 32x32x16
      __builtin_amdgcn_s_setprio(1);
#pragma unroll
      for (int db = 0; db < 4; ++db)
#pragma unroll
        for (int s = 0; s < 4; ++s) {
          const bf16x8 vf = *(const bf16x8*)(&Vs[cur][((db * 4 + s) * 64 + lane) * 8]);
          o[db] = mfma32(vf, pf[s], o[db]);
        }
      __builtin_amdgcn_s_setprio(0);
    }

    // one barrier per tile: implicit vmcnt(0) drain = next tile staged,
    // and all waves done reading buf[cur] before it is overwritten.
    __syncthreads();
    cur ^= 1;
  }

  // ---- epilogue: pair-combine l, normalize, store (O^T: row=d, col=q)
  {
    const float lt = l_i + __shfl_xor(l_i, 32);
    const float inv = 1.0f / lt;
    __bf16* yrow = y + (size_t)(b * Tn + qg) * 2048 + h * 128;
#pragma unroll
    for (int db = 0; db < 4; ++db)
#pragma unroll
      for (int g2 = 0; g2 < 4; ++g2) {
        bf16x4 ov;
#pragma unroll
        for (int j = 0; j < 4; ++j) ov[j] = (__bf16)(o[db][4 * g2 + j] * inv);
        *(bf16x4*)(yrow + db * 32 + 8 * g2 + 4 * hi) = ov;
      }
  }
}

// ---------------------------------------------------------------- launch
extern "C" void kernel_launch(void* const* d_in, const int* in_sizes, int n_in,
                              void* d_out, int out_size, void* d_ws, size_t ws_size,
                              hipStream_t stream) {
  (void)in_sizes; (void)n_in; (void)out_size; (void)ws_size;
  const float* x  = (const float*)d_in[0];
  const float* Wq = (const float*)d_in[1];
  const float* Wk = (const float*)d_in[2];
  const float* Wv = (const float*)d_in[3];
  const float* Wo = (const float*)d_in[4];
  float* out = (float*)d_out;

  __bf16* xb  = (__bf16*)d_ws;                  // [4096][2048]; y aliases after gemm1
  __bf16* y   = xb;
  __bf16* WT  = xb + (size_t)4096 * 2048;       // [3072][2048]
  __bf16* WoT = WT;                             // [2048][2048] aliases after gemm1
  __bf16* VtG = WT + (size_t)2048 * 2048;       // [8][128][2048]
  __bf16* qkv = WT + (size_t)3072 * 2048;       // [4096][3072]
  float* tab  = (float*)VtG;                    // 1 MB cos/sin table; written AFTER
                                                // gemm1 (region dead), read by rope,
                                                // then overwritten by transpose_v.

  convert_f32_bf16<<<(4096 * 2048 / 4 + 255) / 256, 256, 0, stream>>>(x, xb, 4096 * 2048 / 4);
  dim3 tb(32, 8);
  transpose_f32_bf16<<<dim3(64, 64), tb, 0, stream>>>(Wq, WT, 2048, 2048);
  transpose_f32_bf16<<<dim3(16, 64), tb, 0, stream>>>(Wk, WT + (size_t)2048 * 2048, 2048, 512);
  transpose_f32_bf16<<<dim3(16, 64), tb, 0, stream>>>(Wv, WT + (size_t)2560 * 2048, 2048, 512);

  gemm_bt<<<dim3(3072 / 128, 4096 / 128), 256, 0, stream>>>(xb, WT, qkv, 2048, 3072, 0);
  rope_table<<<2048, 64, 0, stream>>>(tab);          // after gemm1: WkT slice is dead
  rope_kernel<<<4096, 256, 0, stream>>>(qkv, tab);

  transpose_v<<<dim3(Tn / 32, 4, 8), tb, 0, stream>>>(qkv, VtG);
  transpose_f32_bf16<<<dim3(64, 64), tb, 0, stream>>>(Wo, WoT, 2048, 2048);

  flash_attn<<<dim3(Tn / 128, 2 * 16), 256, 0, stream>>>(qkv, VtG, y);
  gemm_bt<<<dim3(2048 / 128, 4096 / 128), 256, 0, stream>>>(y, WoT, out, 2048, 2048, 1);
}